// Round 2
// baseline (428.043 us; speedup 1.0000x reference)
//
#include <hip/hip_runtime.h>
#include <cstdint>

#define T_TOKENS 32768
#define D_MODEL  2048
#define N_EXP    64
#define BM       64
#define BK       64
#define CHUNKS   (D_MODEL / BK)   // 32
#define LDK      (BK + 8)         // 72 ushorts/row: stride 144B -> no excess LDS conflicts (verified pattern r1)

typedef short bf16x8 __attribute__((ext_vector_type(8)));
typedef unsigned short u16x8 __attribute__((ext_vector_type(8)));
typedef float f32x4 __attribute__((ext_vector_type(4)));

__device__ __forceinline__ unsigned short f2bf(float f) {
    union { float f; unsigned int u; } c; c.f = f;
    unsigned int u = c.u;
    u += 0x7fffu + ((u >> 16) & 1u);   // RNE
    return (unsigned short)(u >> 16);
}
__device__ __forceinline__ float bf2f(unsigned short h) {
    union { float f; unsigned int u; } c; c.u = ((unsigned int)h) << 16;
    return c.f;
}

// split 8 f32 into 3 bf16 terms each: f ~= h + m + l  (residual ~2^-27 |f|)
__device__ __forceinline__ void split3(const float4& a, const float4& b,
                                       u16x8& h, u16x8& m, u16x8& l) {
    float f[8] = {a.x, a.y, a.z, a.w, b.x, b.y, b.z, b.w};
#pragma unroll
    for (int i = 0; i < 8; ++i) {
        unsigned short hh = f2bf(f[i]);
        float r1 = f[i] - bf2f(hh);
        unsigned short mm = f2bf(r1);
        float r2 = r1 - bf2f(mm);
        unsigned short ll = f2bf(r2);
        h[i] = hh; m[i] = mm; l[i] = ll;
    }
}

// ---- prep: split W once into B-fragment-packed bf16 h/m/l (768 KB in d_ws, L2-resident) ----
// layout: Wpk[(kstep*4 + j)*1536 + part*512 + lane*8 .. +8], kstep in [0,64), j in [0,4)
// so each (kstep,j,part) is one contiguous 1 KB wave-load: lane -> expert j*16+(lane&15), k = kstep*32+(lane>>4)*8
__global__ void router_prep(const float* __restrict__ W, unsigned short* __restrict__ Wpk) {
    const int t = blockIdx.x * 256 + threadIdx.x;    // 16384 threads
    const int lane = t & 63;
    const int sj = t >> 6;                            // kstep*4 + j
    const int e  = (sj & 3) * 16 + (lane & 15);
    const int k0 = (sj >> 2) * 32 + (lane >> 4) * 8;
    const float* src = W + (size_t)e * D_MODEL + k0;
    float4 f0 = *(const float4*)src;
    float4 f1 = *(const float4*)(src + 4);
    u16x8 h, m, l;
    split3(f0, f1, h, m, l);
    unsigned short* dst = Wpk + (size_t)sj * 1536 + lane * 8;
    *(u16x8*)(dst)        = h;
    *(u16x8*)(dst + 512)  = m;
    *(u16x8*)(dst + 1024) = l;
}

#define LOADX(R, CH) do {                                                     \
    _Pragma("unroll") for (int p_ = 0; p_ < 2; ++p_) {                        \
        const float* s_ = xg + (size_t)p_ * 32 * D_MODEL + (CH) * BK;         \
        R[p_][0] = *(const float4*)s_;                                        \
        R[p_][1] = *(const float4*)(s_ + 4);                                  \
    } } while (0)

#define CONV(R, BUF) do {                                                     \
    _Pragma("unroll") for (int p_ = 0; p_ < 2; ++p_) {                        \
        u16x8 h_, m_, l_;                                                     \
        split3(R[p_][0], R[p_][1], h_, m_, l_);                               \
        const int o_ = (rid + p_ * 32) * LDK + kq * 8;                        \
        *(u16x8*)&Asm[BUF][0][o_] = h_;                                       \
        *(u16x8*)&Asm[BUF][1][o_] = m_;                                       \
        *(u16x8*)&Asm[BUF][2][o_] = l_;                                       \
    } } while (0)

#define COMPUTE(CH, BUF) do {                                                 \
    _Pragma("unroll") for (int ks_ = 0; ks_ < 2; ++ks_) {                     \
        const int ko_ = ks_ * 32 + kq8;                                       \
        bf16x8 ah_ = *(const bf16x8*)&Asm[BUF][0][aoff + ko_];                \
        bf16x8 am_ = *(const bf16x8*)&Asm[BUF][1][aoff + ko_];                \
        bf16x8 al_ = *(const bf16x8*)&Asm[BUF][2][aoff + ko_];                \
        _Pragma("unroll") for (int j_ = 0; j_ < 4; ++j_) {                    \
            const unsigned short* wq_ = wlane + (size_t)(((CH)*2 + ks_)*4 + j_) * 1536; \
            bf16x8 bh_ = *(const bf16x8*)(wq_);                               \
            bf16x8 bm_ = *(const bf16x8*)(wq_ + 512);                         \
            bf16x8 bl_ = *(const bf16x8*)(wq_ + 1024);                        \
            acc[j_] = __builtin_amdgcn_mfma_f32_16x16x32_bf16(ah_, bh_, acc[j_], 0, 0, 0); \
            acc[j_] = __builtin_amdgcn_mfma_f32_16x16x32_bf16(am_, bh_, acc[j_], 0, 0, 0); \
            acc[j_] = __builtin_amdgcn_mfma_f32_16x16x32_bf16(ah_, bm_, acc[j_], 0, 0, 0); \
            acc[j_] = __builtin_amdgcn_mfma_f32_16x16x32_bf16(al_, bh_, acc[j_], 0, 0, 0); \
            acc[j_] = __builtin_amdgcn_mfma_f32_16x16x32_bf16(am_, bm_, acc[j_], 0, 0, 0); \
            acc[j_] = __builtin_amdgcn_mfma_f32_16x16x32_bf16(ah_, bl_, acc[j_], 0, 0, 0); \
        }                                                                     \
    } } while (0)

__global__ __launch_bounds__(256, 2) void router_gemm(
    const float* __restrict__ x, const unsigned short* __restrict__ Wpk,
    const float* __restrict__ b, float* __restrict__ logits)
{
    __shared__ unsigned short Asm[2][3][BM * LDK];   // 55296 B -> 2 blocks/CU

    const int tid = threadIdx.x;
    const int t0  = blockIdx.x * BM;
    const int kq  = tid & 7;        // k-octet within row
    const int rid = tid >> 3;       // rows rid, rid+32

    const float* xg = x + (size_t)(t0 + rid) * D_MODEL + kq * 8;

    const int lane = tid & 63;
    const int w    = tid >> 6;          // wave id -> 16-token sub-tile
    const int ln   = lane & 15;
    const int kq8  = (lane >> 4) * 8;
    const int aoff = (w * 16 + ln) * LDK;
    const unsigned short* wlane = Wpk + lane * 8;

    f32x4 acc[4];
#pragma unroll
    for (int j = 0; j < 4; ++j) acc[j] = (f32x4)(0.f);

    float4 ra[2][2], rb[2][2];

    // prologue: L0 <- chunk0, rb <- chunk1
    LOADX(ra, 0);
    CONV(ra, 0);
    LOADX(rb, 1);
    __syncthreads();

    // steady state: one barrier per chunk; loads for c+2 in flight across the
    // whole iteration (drained only by the compiler's vmcnt(0) at the barrier)
    for (int cc = 0; cc < CHUNKS; cc += 2) {
        if (cc + 2 < CHUNKS) LOADX(ra, cc + 2);
        CONV(rb, 1);                       // chunk cc+1 -> buf1
        COMPUTE(cc, 0);
        __syncthreads();

        if (cc + 3 < CHUNKS) LOADX(rb, cc + 3);
        if (cc + 2 < CHUNKS) CONV(ra, 0);  // chunk cc+2 -> buf0
        COMPUTE(cc + 1, 1);
        __syncthreads();
    }

    // epilogue: + bias, / temperature, store logits
    float bias[4];
#pragma unroll
    for (int j = 0; j < 4; ++j) bias[j] = b[j * 16 + ln];
    const int trow = w * 16 + (lane >> 4) * 4;   // C layout: row=(l>>4)*4+r, col=l&15
#pragma unroll
    for (int j = 0; j < 4; ++j) {
#pragma unroll
        for (int r = 0; r < 4; ++r) {
            float v = (acc[j][r] + bias[j]) / 0.1f;
            logits[(size_t)(t0 + trow + r) * N_EXP + j * 16 + ln] = v;
        }
    }
}

// top-8 of 64 per token; 8 lanes per token; jax tie-break (descending, lowest index first)
__global__ __launch_bounds__(256) void router_topk(
    const float* __restrict__ logits, float* __restrict__ probs, float* __restrict__ idxs)
{
    const int tid  = threadIdx.x;
    const int t    = blockIdx.x * 32 + (tid >> 3);
    const int s    = tid & 7;
    const int lane = tid & 63;

    const float* row = logits + (size_t)t * 64 + s * 8;
    float4 v0 = *(const float4*)row;
    float4 v1 = *(const float4*)(row + 4);
    float v[8] = {v0.x, v0.y, v0.z, v0.w, v1.x, v1.y, v1.z, v1.w};

    float sel_v = 0.f; int sel_i = 0;
#pragma unroll
    for (int p = 0; p < 8; ++p) {
        float bm = v[0]; int bi = s * 8;
#pragma unroll
        for (int i = 1; i < 8; ++i) {
            bool g = v[i] > bm;             // strict: keeps lowest index on ties
            bm = g ? v[i] : bm;
            bi = g ? s * 8 + i : bi;
        }
#pragma unroll
        for (int d = 1; d < 8; d <<= 1) {
            float om = __shfl_xor(bm, d);
            int   oi = __shfl_xor(bi, d);
            bool take = (om > bm) || (om == bm && oi < bi);
            bm = take ? om : bm;
            bi = take ? oi : bi;
        }
        if (s == p) { sel_v = bm; sel_i = bi; }
#pragma unroll
        for (int i = 0; i < 8; ++i)
            if (s * 8 + i == bi) v[i] = -__builtin_inff();   // consume (static indexing)
    }

    float mx = __shfl(sel_v, lane & ~7);     // pass-0 winner = row max
    float wgt = expf(sel_v - mx);
    float sum = wgt;
#pragma unroll
    for (int d = 1; d < 8; d <<= 1) sum += __shfl_xor(sum, d);

    probs[(size_t)t * 8 + s] = wgt / sum;    // full-softmax denominator cancels
    idxs [(size_t)t * 8 + s] = (float)sel_i;
}

extern "C" void kernel_launch(void* const* d_in, const int* in_sizes, int n_in,
                              void* d_out, int out_size, void* d_ws, size_t ws_size,
                              hipStream_t stream) {
    const float* x = (const float*)d_in[0];
    const float* W = (const float*)d_in[1];
    const float* b = (const float*)d_in[2];
    float* out    = (float*)d_out;
    float* logits = out;
    float* probs  = out + (size_t)T_TOKENS * N_EXP;
    float* idxs   = probs + (size_t)T_TOKENS * 8;
    unsigned short* Wpk = (unsigned short*)d_ws;     // 768 KB

    router_prep<<<dim3(64),            dim3(256), 0, stream>>>(W, Wpk);
    router_gemm<<<dim3(T_TOKENS / BM), dim3(256), 0, stream>>>(x, Wpk, b, logits);
    router_topk<<<dim3(T_TOKENS / 32), dim3(256), 0, stream>>>(logits, probs, idxs);
}

// Round 5
// 419.423 us; speedup vs baseline: 1.0206x; 1.0206x over previous
//
#include <hip/hip_runtime.h>
#include <cstdint>

#define T_TOKENS 32768
#define D_MODEL  2048
#define N_EXP    64
#define KSTEPS   (D_MODEL / 32)   // 64 MFMA k-steps of 32

typedef short bf16x8 __attribute__((ext_vector_type(8)));
typedef float f32x4 __attribute__((ext_vector_type(4)));

__device__ __forceinline__ unsigned short f2bf(float f) {
    union { float f; unsigned int u; } c; c.f = f;
    unsigned int u = c.u;
    u += 0x7fffu + ((u >> 16) & 1u);   // RNE
    return (unsigned short)(u >> 16);
}
__device__ __forceinline__ float bf2f(unsigned short h) {
    union { float f; unsigned int u; } c; c.u = ((unsigned int)h) << 16;
    return c.f;
}

// split 8 f32 -> 3 bf16 terms: f ~= h + m + l (residual ~2^-27 |f|)
__device__ __forceinline__ void split3(const float4& a, const float4& b,
                                       bf16x8& h, bf16x8& m, bf16x8& l) {
    float f[8] = {a.x, a.y, a.z, a.w, b.x, b.y, b.z, b.w};
    union { bf16x8 v; unsigned short s[8]; } H, M, L;
#pragma unroll
    for (int i = 0; i < 8; ++i) {
        unsigned short hh = f2bf(f[i]);
        float r1 = f[i] - bf2f(hh);
        unsigned short mm = f2bf(r1);
        float r2 = r1 - bf2f(mm);
        H.s[i] = hh; M.s[i] = mm; L.s[i] = f2bf(r2);
    }
    h = H.v; m = M.v; l = L.v;
}

// ---- prep: W -> fragment-packed bf16 h/m/l (768 KB in d_ws, L2-resident) ----
// unit sj = ks*4 + j (1536 ushorts): [0,512) h, [512,1024) m, [1024,1536) l.
// lane -> expert j*16+(lane&15), k = ks*32+(lane>>4)*8 (+0..7)
__global__ void router_prep(const float* __restrict__ W, unsigned short* __restrict__ Wpk) {
    const int t = blockIdx.x * 256 + threadIdx.x;    // 16384 threads
    const int lane = t & 63;
    const int sj = t >> 6;
    const int e  = (sj & 3) * 16 + (lane & 15);
    const int k0 = (sj >> 2) * 32 + (lane >> 4) * 8;
    const float* src = W + (size_t)e * D_MODEL + k0;
    float4 f0 = *(const float4*)src;
    float4 f1 = *(const float4*)(src + 4);
    bf16x8 h, m, l;
    split3(f0, f1, h, m, l);
    unsigned short* dst = Wpk + (size_t)sj * 1536 + lane * 8;
    *(bf16x8*)(dst)        = h;
    *(bf16x8*)(dst + 512)  = m;
    *(bf16x8*)(dst + 1024) = l;
}

// ---- gemm: no LDS, no barriers; 16 tokens x 64 experts per wave ----
#define LOADS(A0, A1, BH, BM, BL, KS) do {                                    \
    const float* ax_ = xg + (KS) * 32;                                        \
    A0 = *(const float4*)ax_;                                                 \
    A1 = *(const float4*)(ax_ + 4);                                           \
    _Pragma("unroll") for (int j_ = 0; j_ < 4; ++j_) {                        \
        const unsigned short* wq_ = wlane + (size_t)((KS) * 4 + j_) * 1536;   \
        BH[j_] = *(const bf16x8*)wq_;                                         \
        BM[j_] = *(const bf16x8*)(wq_ + 512);                                 \
        BL[j_] = *(const bf16x8*)(wq_ + 1024);                                \
    } } while (0)

// 6 products: hh -> accP (even/odd chain), {mh,hm,lh,mm,hl} -> accC
#define COMP(A0, A1, BH, BM, BL, ACCP) do {                                   \
    bf16x8 ah_, am_, al_;                                                     \
    split3(A0, A1, ah_, am_, al_);                                            \
    _Pragma("unroll") for (int j_ = 0; j_ < 4; ++j_) {                        \
        ACCP[j_] = __builtin_amdgcn_mfma_f32_16x16x32_bf16(ah_, BH[j_], ACCP[j_], 0, 0, 0); \
        accC[j_] = __builtin_amdgcn_mfma_f32_16x16x32_bf16(am_, BH[j_], accC[j_], 0, 0, 0); \
        accC[j_] = __builtin_amdgcn_mfma_f32_16x16x32_bf16(ah_, BM[j_], accC[j_], 0, 0, 0); \
        accC[j_] = __builtin_amdgcn_mfma_f32_16x16x32_bf16(al_, BH[j_], accC[j_], 0, 0, 0); \
        accC[j_] = __builtin_amdgcn_mfma_f32_16x16x32_bf16(am_, BM[j_], accC[j_], 0, 0, 0); \
        accC[j_] = __builtin_amdgcn_mfma_f32_16x16x32_bf16(ah_, BL[j_], accC[j_], 0, 0, 0); \
    } } while (0)

__global__ __launch_bounds__(256, 2) void router_gemm(
    const float* __restrict__ x, const unsigned short* __restrict__ Wpk,
    const float* __restrict__ b, float* __restrict__ logits)
{
    const int tid  = threadIdx.x;
    const int lane = tid & 63;
    const int w    = tid >> 6;                    // wave id -> 16-token group
    const int t0   = blockIdx.x * 64 + w * 16;
    const int ln   = lane & 15;

    // A-fragment source: row = lane&15 (token), k-octet = (lane>>4)*8
    const float* xg = x + (size_t)(t0 + ln) * D_MODEL + (lane >> 4) * 8;
    const unsigned short* wlane = Wpk + lane * 8;

    f32x4 accP0[4], accP1[4], accC[4];
#pragma unroll
    for (int j = 0; j < 4; ++j) {
        accP0[j] = (f32x4)(0.f); accP1[j] = (f32x4)(0.f); accC[j] = (f32x4)(0.f);
    }

    // two named register stages (static indexing only)
    float4 a00, a01, a10, a11;
    bf16x8 bh0[4], bm0[4], bl0[4], bh1[4], bm1[4], bl1[4];

    LOADS(a00, a01, bh0, bm0, bl0, 0);
    LOADS(a10, a11, bh1, bm1, bl1, 1);

    for (int ks = 0; ks < KSTEPS - 2; ks += 2) {
        COMP(a00, a01, bh0, bm0, bl0, accP0);     // even k-step (stage 0)
        LOADS(a00, a01, bh0, bm0, bl0, ks + 2);   // refill stage 0
        COMP(a10, a11, bh1, bm1, bl1, accP1);     // odd k-step  (stage 1)
        LOADS(a10, a11, bh1, bm1, bl1, ks + 3);   // refill stage 1
    }
    COMP(a00, a01, bh0, bm0, bl0, accP0);         // k-step 62
    COMP(a10, a11, bh1, bm1, bl1, accP1);         // k-step 63

    // epilogue: + bias, / temperature  (C layout: row=(l>>4)*4+r, col=l&15)
    float bias[4];
#pragma unroll
    for (int j = 0; j < 4; ++j) bias[j] = b[j * 16 + ln];
    const int trow = (lane >> 4) * 4;
#pragma unroll
    for (int j = 0; j < 4; ++j) {
#pragma unroll
        for (int r = 0; r < 4; ++r) {
            float v = (accP0[j][r] + accP1[j][r] + (accC[j][r] + bias[j])) / 0.1f;
            logits[(size_t)(t0 + trow + r) * N_EXP + j * 16 + ln] = v;
        }
    }
}

// top-8 of 64 per token; 8 lanes/token; jax tie-break (descending, lowest index first)
__global__ __launch_bounds__(256) void router_topk(
    const float* __restrict__ logits, float* __restrict__ probs, float* __restrict__ idxs)
{
    const int tid  = threadIdx.x;
    const int t    = blockIdx.x * 32 + (tid >> 3);
    const int s    = tid & 7;
    const int lane = tid & 63;

    const float* row = logits + (size_t)t * 64 + s * 8;
    float4 v0 = *(const float4*)row;
    float4 v1 = *(const float4*)(row + 4);
    float v[8] = {v0.x, v0.y, v0.z, v0.w, v1.x, v1.y, v1.z, v1.w};

    float sel_v = 0.f; int sel_i = 0;
#pragma unroll
    for (int p = 0; p < 8; ++p) {
        float bm = v[0]; int bi = s * 8;
#pragma unroll
        for (int i = 1; i < 8; ++i) {
            bool g = v[i] > bm;             // strict: keeps lowest index on ties
            bm = g ? v[i] : bm;
            bi = g ? s * 8 + i : bi;
        }
#pragma unroll
        for (int d = 1; d < 8; d <<= 1) {
            float om = __shfl_xor(bm, d);
            int   oi = __shfl_xor(bi, d);
            bool take = (om > bm) || (om == bm && oi < bi);
            bm = take ? om : bm;
            bi = take ? oi : bi;
        }
        if (s == p) { sel_v = bm; sel_i = bi; }
#pragma unroll
        for (int i = 0; i < 8; ++i)
            if (s * 8 + i == bi) v[i] = -__builtin_inff();   // consume (static indexing)
    }

    float mx = __shfl(sel_v, lane & ~7);     // pass-0 winner = row max
    float wgt = expf(sel_v - mx);
    float sum = wgt;
#pragma unroll
    for (int d = 1; d < 8; d <<= 1) sum += __shfl_xor(sum, d);

    probs[(size_t)t * 8 + s] = wgt / sum;    // full-softmax denominator cancels
    idxs [(size_t)t * 8 + s] = (float)sel_i;
}

extern "C" void kernel_launch(void* const* d_in, const int* in_sizes, int n_in,
                              void* d_out, int out_size, void* d_ws, size_t ws_size,
                              hipStream_t stream) {
    const float* x = (const float*)d_in[0];
    const float* W = (const float*)d_in[1];
    const float* b = (const float*)d_in[2];
    float* out    = (float*)d_out;
    float* logits = out;
    float* probs  = out + (size_t)T_TOKENS * N_EXP;
    float* idxs   = probs + (size_t)T_TOKENS * 8;
    unsigned short* Wpk = (unsigned short*)d_ws;     // 768 KB

    router_prep<<<dim3(64),             dim3(256), 0, stream>>>(W, Wpk);
    router_gemm<<<dim3(T_TOKENS / 64),  dim3(256), 0, stream>>>(x, Wpk, b, logits);
    router_topk<<<dim3(T_TOKENS / 32),  dim3(256), 0, stream>>>(logits, probs, idxs);
}